// Round 1
// 294.862 us; speedup vs baseline: 1.0098x; 1.0098x over previous
//
#include <hip/hip_runtime.h>
#include <math.h>

#define IMGD 224
#define HW 50176      // 224*224
#define NK 100
#define NB 8
#define OUT_PER_B 76800   // 100*16*16*3 = 300*256
#define NCHUNK 131        // OpenBLAS k-blocking of 50176: 129x384, 320, 320
#define MSTR 13           // mask/ppk row stride (13 coprime 32: no bank conflicts)

// R12/R14/R18 lesson: cross-block reduction inside a kernel is unaffordable on
// gfx950 in ANY form (fence ~1.5us/block serialized; redundant recompute ~12us/
// iter of L2 traffic). The separate tiny combine dispatch is the optimum; the
// kernel boundary is the only cheap coherence point.

static __device__ __forceinline__ float ratio_f32() {
  return (float)(10.0 / sqrt(224.0 * 224.0 / 100.0));
}

// distance op sequence — the single source of truth for bit-exactness
static __device__ __forceinline__ float dist5s(float f0, float f1, float f2,
                                               float f3, float f4, float fsq,
                                               float c0, float c1, float c2,
                                               float c3, float c4, float q) {
  float dot = __fmul_rn(f0, c0);
  dot = __fmaf_rn(f1, c1, dot);
  dot = __fmaf_rn(f2, c2, dot);
  dot = __fmaf_rn(f3, c3, dot);
  dot = __fmaf_rn(f4, c4, dot);
  return __fsub_rn(__fadd_rn(fsq, q), __fmul_rn(2.0f, dot));
}

static __device__ __forceinline__ float fsq5(float f0, float f1, float f2,
                                             float f3, float f4) {
  float s = __fmul_rn(f0, f0);
  s = __fadd_rn(s, __fmul_rn(f1, f1));
  s = __fadd_rn(s, __fmul_rn(f2, f2));
  s = __fadd_rn(s, __fmul_rn(f3, f3));
  s = __fadd_rn(s, __fmul_rn(f4, f4));
  return s;
}

// ---------- fused assign+partial: 1 chunk per 128-thread block ----------
// flag==0: self-init centers in LDS (identical FP ops to the old setup kernel;
// block c==0 persists them for combine#1's cnt==0 carryover). flag==1: read
// centers/c2 from global (written by the previous combine dispatch).
// flag==0 dispatch carries 16 extra blocks (c==NCHUNK) that materialize the
// resize matrix A into global ws ONCE: the 128-thread tree replicates the old
// 256-thread reduction pairing exactly (level-128 add first) => Z and all A
// values bit-identical to the per-block computation embed used to do.
// Pruning: UB = min_k(dy_max^2+dx_max^2+3), keep k iff dy_min^2+dx_min^2 <=
// UB+1.0 (slack >> f32 rounding) => argmin + ascending-k first-index ties
// bit-preserved. Compaction add chains ascending-pixel (bit-exact).
__global__ void __launch_bounds__(128, 4) iter_kernel(
    const float* __restrict__ x, float* __restrict__ centers,
    const float* __restrict__ c2g, float* __restrict__ partials, int flag,
    float* __restrict__ Ag) {
  __shared__ float4 ck4[NK];
  __shared__ float2 ck2[NK];
  __shared__ unsigned int mask[NK * MSTR];
  __shared__ unsigned short ppk[NK * MSTR];
  __shared__ float4 cval4[384];
  __shared__ float  cvalf[384];
  __shared__ int cnt[128];
  __shared__ int offx[128];
  __shared__ int wtot;
  __shared__ float ubpart[12][10];
  __shared__ float ubg[12];
  __shared__ unsigned int candm[12][4];
  __shared__ unsigned char clist[12][104];
  __shared__ int clen[12];
  __shared__ float ared[128];
  int c = blockIdx.x, b = blockIdx.y;
  int tid = threadIdx.x;

  if (c >= NCHUNK) {
    // ---- A-setup blocks (present only in the flag==0 dispatch) ----
    // block (NCHUNK, b) computes A rows 2b and 2b+1 into Ag[16][224].
    for (int rr = 0; rr < 2; ++rr) {
      int p = 2 * b + rr;
      float cp = (p + 0.5f) * 14.0f - 0.5f;
      // level s=128 of the old 256-wide tree: red[t] = tri(t) + tri(t+128)
      float trip0, trip1 = 0.0f;
      {
        float xd = fabsf(cp - (float)tid) / 14.0f;     // tid < 128 < 224
        trip0 = fmaxf(0.0f, 1.0f - xd);
      }
      int t2 = tid + 128;
      if (t2 < IMGD) {
        float xd = fabsf(cp - (float)t2) / 14.0f;
        trip1 = fmaxf(0.0f, 1.0f - xd);
      }
      ared[tid] = trip0 + trip1;
      __syncthreads();
      for (int s = 64; s > 0; s >>= 1) {
        if (tid < s) ared[tid] += ared[tid + s];
        __syncthreads();
      }
      float Zp = ared[0];
      __syncthreads();
      {
        float xd = fabsf(cp - (float)tid) / 14.0f;
        Ag[p * IMGD + tid] = fmaxf(0.0f, 1.0f - xd) / Zp;  // same expr as before
      }
      if (t2 < IMGD) {
        float xd = fabsf(cp - (float)t2) / 14.0f;
        Ag[p * IMGD + t2] = fmaxf(0.0f, 1.0f - xd) / Zp;
      }
      __syncthreads();
    }
    return;
  }

  int start = (c < 129) ? c * 384 : 49536 + (c - 129) * 320;
  int len   = (c < 129) ? 384 : 320;

  const float ratio = ratio_f32();
  const float* x0 = x + (size_t)b * 3 * HW;
  if (flag == 0) {
    // self-init: same ops as the old setup kernel => identical center values
    if (tid < NK) {
      int gy = tid / 10, gx = tid - 10 * (tid / 10);
      int cy = (int)((gy + 0.5) * 224.0 / 10.0);  // trunc like .astype(int32)
      int cx = (int)((gx + 0.5) * 224.0 / 10.0);
      int i = cy * IMGD + cx;
      float c0 = x0[i], c1 = x0[HW + i], c2 = x0[2 * HW + i];
      float c3 = __fmul_rn((float)cy, ratio);
      float c4 = __fmul_rn((float)cx, ratio);
      float s = __fmul_rn(c0, c0);
      s = __fadd_rn(s, __fmul_rn(c1, c1));
      s = __fadd_rn(s, __fmul_rn(c2, c2));
      s = __fadd_rn(s, __fmul_rn(c3, c3));
      s = __fadd_rn(s, __fmul_rn(c4, c4));
      ck4[tid] = make_float4(c0, c1, c2, c3);
      ck2[tid] = make_float2(c4, s);
      if (c == 0) {   // persist for combine#1's cnt==0 carryover
        float* oc = centers + ((size_t)b * NK + tid) * 5;
        oc[0] = c0; oc[1] = c1; oc[2] = c2; oc[3] = c3; oc[4] = c4;
      }
    }
  } else {
    const float* cb = centers + (size_t)b * NK * 5;
    const float* c2b = c2g + (size_t)b * NK;
    if (tid < NK) {
      ck4[tid] = make_float4(cb[tid*5+0], cb[tid*5+1], cb[tid*5+2], cb[tid*5+3]);
      ck2[tid] = make_float2(cb[tid*5+4], c2b[tid]);
    }
  }
  for (int t = tid; t < NK * MSTR; t += 128) mask[t] = 0u;
  if (tid < 48) candm[tid >> 2][tid & 3] = 0u;

  // pixel loads early (no LDS dependence) — overlap with pruning phases
  float f0[3], f1[3], f2[3], f3[3], f4[3], fq[3];
  bool vld[3];
  for (int r = 0; r < 3; ++r) {
    int t = tid + r * 128;
    vld[r] = (t < len);
    int i = start + (vld[r] ? t : 0);
    int y = i / IMGD, xw = i - y * IMGD;
    f0[r] = x0[i]; f1[r] = x0[HW + i]; f2[r] = x0[2 * HW + i];
    f3[r] = __fmul_rn((float)y, ratio);
    f4[r] = __fmul_rn((float)xw, ratio);
    fq[r] = fsq5(f0[r], f1[r], f2[r], f3[r], f4[r]);
  }
  __syncthreads();

  // UB phase: thread (g,kb) scans 10 centers; group bounds in-register
  if (tid < 120) {
    int g = tid / 10, kb = tid - 10 * g;
    int i0 = start + g * 32, i1 = i0 + 31;
    int ymin = i0 / IMGD, ymax = i1 / IMGD;
    int cmin = (ymin == ymax) ? (i0 - ymin * IMGD) : 0;
    int cmax = (ymin == ymax) ? (i1 - ymax * IMGD) : (IMGD - 1);
    float f3mn = __fmul_rn((float)ymin, ratio);
    float f3mx = __fmul_rn((float)ymax, ratio);
    float f4mn = __fmul_rn((float)cmin, ratio);
    float f4mx = __fmul_rn((float)cmax, ratio);
    float mn = 3.4e38f;
    for (int k = kb * 10; k < kb * 10 + 10; ++k) {
      float c3 = ck4[k].w, c4 = ck2[k].x;
      float dy = fmaxf(fabsf(c3 - f3mn), fabsf(c3 - f3mx));
      float dx = fmaxf(fabsf(c4 - f4mn), fabsf(c4 - f4mx));
      mn = fminf(mn, dy * dy + dx * dx + 3.0f);
    }
    ubpart[g][kb] = mn;
  }
  __syncthreads();
  if (tid < 12) {
    float mn = ubpart[tid][0];
    for (int j = 1; j < 10; ++j) mn = fminf(mn, ubpart[tid][j]);
    ubg[tid] = mn + 1.0f;   // slack >> all f32 rounding at these magnitudes
  }
  __syncthreads();
  if (tid < 120) {
    int g = tid / 10, kb = tid - 10 * g;
    int i0 = start + g * 32, i1 = i0 + 31;
    int ymin = i0 / IMGD, ymax = i1 / IMGD;
    int cmin = (ymin == ymax) ? (i0 - ymin * IMGD) : 0;
    int cmax = (ymin == ymax) ? (i1 - ymax * IMGD) : (IMGD - 1);
    float f3mn = __fmul_rn((float)ymin, ratio);
    float f3mx = __fmul_rn((float)ymax, ratio);
    float f4mn = __fmul_rn((float)cmin, ratio);
    float f4mx = __fmul_rn((float)cmax, ratio);
    float lim = ubg[g];
    for (int k = kb * 10; k < kb * 10 + 10; ++k) {
      float c3 = ck4[k].w, c4 = ck2[k].x;
      float dy = fmaxf(0.0f, fmaxf(f3mn - c3, c3 - f3mx));
      float dx = fmaxf(0.0f, fmaxf(f4mn - c4, c4 - f4mx));
      if (dy * dy + dx * dx <= lim)
        atomicOr(&candm[g][k >> 5], 1u << (k & 31));
    }
  }
  __syncthreads();
  // dense ascending-k candidate lists
  if (tid < 12) {
    int len2 = 0;
    for (int w = 0; w < 4; ++w) {
      unsigned int m = candm[tid][w];
      while (m) {
        int j = __ffs(m) - 1;
        m &= m - 1;
        clist[tid][len2++] = (unsigned char)(w * 32 + j);
      }
    }
    clen[tid] = len2;
  }
  __syncthreads();

  // pruned distance loop: candidates ascending k (first-index ties safe)
  float best[3]; int bk[3];
  for (int r = 0; r < 3; ++r) {
    best[r] = 3.4e38f; bk[r] = 0;
    int t = tid + r * 128;
    int g = (t < 384) ? (t >> 5) : 0;
    int n = clen[g];
    for (int j = 0; j < n; ++j) {
      int k = clist[g][j];
      float4 a4 = ck4[k];
      float2 a2 = ck2[k];
      float d = dist5s(f0[r], f1[r], f2[r], f3[r], f4[r], fq[r],
                       a4.x, a4.y, a4.z, a4.w, a2.x, a2.y);
      if (d < best[r]) { best[r] = d; bk[r] = k; }
    }
  }
  for (int r = 0; r < 3; ++r) {
    int t = tid + r * 128;
    if (vld[r]) atomicOr(&mask[bk[r] * MSTR + (t >> 5)], 1u << (t & 31));
  }
  __syncthreads();

  // per-k cumulative popcounts (stride-13 rows: conflict-free)
  int myCnt = 0;
  if (tid < NK) {
    int s = 0;
    for (int g = 0; g < 12; ++g) {
      ppk[tid * MSTR + g] = (unsigned short)s;
      s += __popc(mask[tid * MSTR + g]);
    }
    myCnt = s;
  }
  cnt[tid] = myCnt;
  __syncthreads();

  // inclusive prefix over 128 counts: shfl per wave + cross-wave fixup
  int v = myCnt;
  for (int d = 1; d < 64; d <<= 1) {
    int u = __shfl_up(v, d, 64);
    if ((tid & 63) >= d) v += u;
  }
  if (tid == 63) wtot = v;
  __syncthreads();
  if (tid >= 64) v += wtot;
  offx[tid] = v;
  __syncthreads();

  // stable VALUE scatter: pos = (off[k]-cnt[k]) + rank_within_k(t)
  for (int r = 0; r < 3; ++r) {
    int t = tid + r * 128;
    if (vld[r]) {
      int g = t >> 5, j = t & 31;
      unsigned int m = mask[bk[r] * MSTR + g];
      int rank = ppk[bk[r] * MSTR + g] + __popc(m & ((1u << j) - 1u));
      int pos = offx[bk[r]] - cnt[bk[r]] + rank;
      cval4[pos] = make_float4(f0[r], f1[r], f2[r], f3[r]);
      cvalf[pos] = f4[r];
    }
  }
  __syncthreads();

  // scan: thread k walks its consecutive compacted range (ascending t)
  if (tid < NK) {
    int n = cnt[tid];
    int base = offx[tid] - n;
    float s0 = 0.f, s1 = 0.f, s2 = 0.f, s3 = 0.f, s4 = 0.f, s5 = 0.f;
    for (int m = 0; m < n; ++m) {
      float4 vv = cval4[base + m];
      float ww = cvalf[base + m];
      s0 = __fadd_rn(s0, vv.x);
      s1 = __fadd_rn(s1, vv.y);
      s2 = __fadd_rn(s2, vv.z);
      s3 = __fadd_rn(s3, vv.w);
      s4 = __fadd_rn(s4, ww);
      s5 += 1.0f;
    }
    // k-major layout [b][k][j][c]: combine reads contiguous
    float* pp = partials + ((size_t)(b * NK + tid) * 6) * NCHUNK + c;
    pp[0 * NCHUNK] = s0; pp[1 * NCHUNK] = s1; pp[2 * NCHUNK] = s2;
    pp[3 * NCHUNK] = s3; pp[4 * NCHUNK] = s4; pp[5 * NCHUNK] = s5;
  }
}

// ---------- combine: one block per (b,k); LDS-staged 131-chains ----------
__global__ void __launch_bounds__(128) combine_update_kernel(
    float* __restrict__ centers, const float* __restrict__ partials,
    float* __restrict__ c2g) {
  __shared__ float st[6 * NCHUNK];
  __shared__ float sums[6];
  __shared__ float newc[5];
  int bk = blockIdx.x;                 // b*NK + k
  int tid = threadIdx.x;
  const float* base = partials + (size_t)bk * 6 * NCHUNK;
  for (int t = tid; t < 6 * NCHUNK; t += 128) st[t] = base[t];
  __syncthreads();
  if (tid < 6) {
    const float* row = st + tid * NCHUNK;
    float s = row[0];                  // C = 0 + chunk0 (exact)
    for (int c = 1; c < NCHUNK; ++c) s = __fadd_rn(s, row[c]);
    sums[tid] = s;
  }
  __syncthreads();
  float cntv = sums[5];
  float* cc = centers + (size_t)bk * 5;
  if (tid < 5) {
    float v;
    if (cntv > 0.0f) {                 // where(cnt>0, new, centers)
      float m = fmaxf(cntv, 1.0f);     // np.maximum(cnt,1.0): exact int in f32
      v = __fdiv_rn(sums[tid], m);
      cc[tid] = v;
    } else {
      v = cc[tid];                     // unchanged center
    }
    newc[tid] = v;
  }
  __syncthreads();
  if (tid == 0) {
    // c2 = sum(centers*centers): rounded products, sequential adds
    float t0 = __fmul_rn(newc[0], newc[0]);
    t0 = __fadd_rn(t0, __fmul_rn(newc[1], newc[1]));
    t0 = __fadd_rn(t0, __fmul_rn(newc[2], newc[2]));
    t0 = __fadd_rn(t0, __fmul_rn(newc[3], newc[3]));
    t0 = __fadd_rn(t0, __fmul_rn(newc[4], newc[4]));
    c2g[bk] = t0;
  }
}

// ---------- labels: final assignment w.r.t. centers_10, written ONCE ----------
// Front half of iter_kernel (identical loads, identical pruning bound,
// identical dist5s op sequence, candidates iterated ascending-k straight out
// of the candm bitmask == same set/order as the dense list) => labels
// bit-identical to the per-window argmin the old embed computed 4x per pixel.
__global__ void __launch_bounds__(128, 4) label_kernel(
    const float* __restrict__ x, const float* __restrict__ centers,
    const float* __restrict__ c2g, unsigned char* __restrict__ labels) {
  __shared__ float4 ck4[NK];
  __shared__ float2 ck2[NK];
  __shared__ float ubpart[12][10];
  __shared__ float ubg[12];
  __shared__ unsigned int candm[12][4];
  int c = blockIdx.x, b = blockIdx.y;
  int tid = threadIdx.x;
  int start = (c < 129) ? c * 384 : 49536 + (c - 129) * 320;
  int len   = (c < 129) ? 384 : 320;

  const float ratio = ratio_f32();
  const float* x0 = x + (size_t)b * 3 * HW;
  const float* cb = centers + (size_t)b * NK * 5;
  const float* c2b = c2g + (size_t)b * NK;
  if (tid < NK) {
    ck4[tid] = make_float4(cb[tid*5+0], cb[tid*5+1], cb[tid*5+2], cb[tid*5+3]);
    ck2[tid] = make_float2(cb[tid*5+4], c2b[tid]);
  }
  if (tid < 48) candm[tid >> 2][tid & 3] = 0u;

  float f0[3], f1[3], f2[3], f3[3], f4[3], fq[3];
  int ii[3];
  bool vld[3];
  for (int r = 0; r < 3; ++r) {
    int t = tid + r * 128;
    vld[r] = (t < len);
    int i = start + (vld[r] ? t : 0);
    ii[r] = i;
    int y = i / IMGD, xw = i - y * IMGD;
    f0[r] = x0[i]; f1[r] = x0[HW + i]; f2[r] = x0[2 * HW + i];
    f3[r] = __fmul_rn((float)y, ratio);
    f4[r] = __fmul_rn((float)xw, ratio);
    fq[r] = fsq5(f0[r], f1[r], f2[r], f3[r], f4[r]);
  }
  __syncthreads();

  if (tid < 120) {
    int g = tid / 10, kb = tid - 10 * g;
    int i0 = start + g * 32, i1 = i0 + 31;
    int ymin = i0 / IMGD, ymax = i1 / IMGD;
    int cmin = (ymin == ymax) ? (i0 - ymin * IMGD) : 0;
    int cmax = (ymin == ymax) ? (i1 - ymax * IMGD) : (IMGD - 1);
    float f3mn = __fmul_rn((float)ymin, ratio);
    float f3mx = __fmul_rn((float)ymax, ratio);
    float f4mn = __fmul_rn((float)cmin, ratio);
    float f4mx = __fmul_rn((float)cmax, ratio);
    float mn = 3.4e38f;
    for (int k = kb * 10; k < kb * 10 + 10; ++k) {
      float c3 = ck4[k].w, c4 = ck2[k].x;
      float dy = fmaxf(fabsf(c3 - f3mn), fabsf(c3 - f3mx));
      float dx = fmaxf(fabsf(c4 - f4mn), fabsf(c4 - f4mx));
      mn = fminf(mn, dy * dy + dx * dx + 3.0f);
    }
    ubpart[g][kb] = mn;
  }
  __syncthreads();
  if (tid < 12) {
    float mn = ubpart[tid][0];
    for (int j = 1; j < 10; ++j) mn = fminf(mn, ubpart[tid][j]);
    ubg[tid] = mn + 1.0f;
  }
  __syncthreads();
  if (tid < 120) {
    int g = tid / 10, kb = tid - 10 * g;
    int i0 = start + g * 32, i1 = i0 + 31;
    int ymin = i0 / IMGD, ymax = i1 / IMGD;
    int cmin = (ymin == ymax) ? (i0 - ymin * IMGD) : 0;
    int cmax = (ymin == ymax) ? (i1 - ymax * IMGD) : (IMGD - 1);
    float f3mn = __fmul_rn((float)ymin, ratio);
    float f3mx = __fmul_rn((float)ymax, ratio);
    float f4mn = __fmul_rn((float)cmin, ratio);
    float f4mx = __fmul_rn((float)cmax, ratio);
    float lim = ubg[g];
    for (int k = kb * 10; k < kb * 10 + 10; ++k) {
      float c3 = ck4[k].w, c4 = ck2[k].x;
      float dy = fmaxf(0.0f, fmaxf(f3mn - c3, c3 - f3mx));
      float dx = fmaxf(0.0f, fmaxf(f4mn - c4, c4 - f4mx));
      if (dy * dy + dx * dx <= lim)
        atomicOr(&candm[g][k >> 5], 1u << (k & 31));
    }
  }
  __syncthreads();

  // pruned distance loop over candm words: k ascending (w asc, ffs asc) —
  // identical candidate sequence to the dense-list version.
  float best[3]; int bk[3];
  for (int r = 0; r < 3; ++r) {
    best[r] = 3.4e38f; bk[r] = 0;
    int t = tid + r * 128;
    int g = (t < 384) ? (t >> 5) : 0;
    for (int w = 0; w < 4; ++w) {
      unsigned int m = candm[g][w];
      while (m) {
        int j = __ffs(m) - 1;
        m &= m - 1;
        int k = (w << 5) + j;
        float4 a4 = ck4[k];
        float2 a2 = ck2[k];
        float d = dist5s(f0[r], f1[r], f2[r], f3[r], f4[r], fq[r],
                         a4.x, a4.y, a4.z, a4.w, a2.x, a2.y);
        if (d < best[r]) { best[r] = d; bk[r] = k; }
      }
    }
  }
  unsigned char* lb = labels + (size_t)b * HW;
  for (int r = 0; r < 3; ++r)
    if (vld[r]) lb[ii[r]] = (unsigned char)bk[r];
}

// ---------- embed (lean): block = (b,p,q); A + labels precomputed ----------
// Prologue is now 56 coalesced A loads + LDS zero (2 barriers). Pixel loop:
// 1 label byte + 3 values + weight + 3 LDS atomics. sk accumulation structure
// and the epilogue store are byte-identical to the previous version.
__global__ void __launch_bounds__(256) embed_kernel(
    const float* __restrict__ x, const unsigned char* __restrict__ labels,
    const float* __restrict__ Ag, float* __restrict__ out) {
  __shared__ float Apv[28];
  __shared__ float Aqv[28];
  __shared__ float sk[NK * 3];
  int b = blockIdx.y;
  int p = blockIdx.x >> 4;
  int q = blockIdx.x & 15;
  int tid = threadIdx.x;

  int h0 = max(0, 14 * p - 7), h1 = min(IMGD - 1, 14 * p + 20);
  int w0 = max(0, 14 * q - 7), w1 = min(IMGD - 1, 14 * q + 20);
  int hl = h1 - h0 + 1, wl = w1 - w0 + 1;
  if (tid < hl) Apv[tid] = Ag[p * IMGD + h0 + tid];
  if (tid < wl) Aqv[tid] = Ag[q * IMGD + w0 + tid];
  for (int t = tid; t < NK * 3; t += 256) sk[t] = 0.0f;
  __syncthreads();

  const float* xb = x + (size_t)b * 3 * HW;
  const unsigned char* lb = labels + (size_t)b * HW;
  int n = hl * wl;
  for (int r = 0; r < 4; ++r) {
    int idx = tid + r * 256;
    if (idx >= n) break;
    int dh = idx / wl;
    int hh = h0 + dh;
    int dw = idx - dh * wl;
    int ww = w0 + dw;
    int i = hh * IMGD + ww;
    float v0 = xb[i], v1 = xb[HW + i], v2 = xb[2 * HW + i];
    int k = lb[i];
    float wgt = Apv[dh] * Aqv[dw];
    atomicAdd(&sk[k * 3 + 0], wgt * v0);
    atomicAdd(&sk[k * 3 + 1], wgt * v1);
    atomicAdd(&sk[k * 3 + 2], wgt * v2);
  }
  __syncthreads();

  float* outb = out + (size_t)b * OUT_PER_B;
  int base = p * 48 + q * 3;
  for (int t = tid; t < NK * 3; t += 256) {
    int k = t / 3, cc = t - 3 * k;
    int f = k * 768 + base + cc;              // flat [K,P,P,C] index
    outb[(f & 255) * 300 + (f >> 8)] = sk[t]; // view(B,300,256) + transpose
  }
}

extern "C" void kernel_launch(void* const* d_in, const int* in_sizes, int n_in,
                              void* d_out, int out_size, void* d_ws, size_t ws_size,
                              hipStream_t stream) {
  const float* x = (const float*)d_in[0];
  float* out = (float*)d_out;
  char* ws = (char*)d_ws;
  // ws layout:
  float* centers        = (float*)(ws + 16384);      // 16000 B
  float* c2g            = (float*)(ws + 49152);      // 3200 B
  float* Ag             = (float*)(ws + 65536);      // 16*224*4 = 14336 B
  unsigned char* labels = (unsigned char*)(ws + 98304); // 8*50176 = 401408 B
  float* partials       = (float*)(ws + 1703936);    // 8*100*6*131*4 = 2515200 B

  dim3 cgrid0(NCHUNK + 1, NB);    // +8 blocks (c==131): A-setup, rows 2b,2b+1
  dim3 cgrid(NCHUNK, NB);         // 131 x 8 — 1048 blocks
  iter_kernel<<<cgrid0, 128, 0, stream>>>(x, centers, c2g, partials, 0, Ag);
  combine_update_kernel<<<NB * NK, 128, 0, stream>>>(centers, partials, c2g);
  for (int it = 1; it < 10; ++it) {
    iter_kernel<<<cgrid, 128, 0, stream>>>(x, centers, c2g, partials, 1, Ag);
    combine_update_kernel<<<NB * NK, 128, 0, stream>>>(centers, partials, c2g);
  }
  label_kernel<<<cgrid, 128, 0, stream>>>(x, centers, c2g, labels);
  dim3 egrid(256, NB);            // (p*16+q) x b
  embed_kernel<<<egrid, 256, 0, stream>>>(x, labels, Ag, out);
}